// Round 4
// baseline (232.566 us; speedup 1.0000x reference)
//
#include <hip/hip_runtime.h>

// ---------------------------------------------------------------------------
// DigitConvolutionalModel: x(32768,784) -> conv3x3(valid) -> 676
//   -> relu(@W1(676,300)+b1) -> relu(@W2(300,300)+b2) -> @W3(300,10)+b3
//
// R4: BARRIER-FREE K-loops. B-frags live in registers (double-buffered),
// loaded straight from global (L2-resident weights). A double-buffered in
// registers from global. No __syncthreads in any K-loop -> no vmcnt(0)
// drains -> loads stay in flight across MFMA phases.
//  - wave tile: 2 m-tiles x 10 n-tiles (32 rows x 160 cols), 256 thr = 4
//    waves = 2 m-groups x 2 n-groups -> block = 64 rows x 320 cols.
//  - gemm1: x fp32 (HBM) A-path, W1eff B-path, h1 bf16 row-major out.
//  - gemm23: h1 bf16 A-path (one dwordx4 = one A-frag), W2 B-path; single
//    barrier pair for the h2 C->A layout exchange through LDS; GEMM3 tiny.
// ---------------------------------------------------------------------------

typedef __bf16 bf16_t;
typedef __bf16 bf16x8 __attribute__((ext_vector_type(8)));
typedef float  f32x4  __attribute__((ext_vector_type(4)));

#define MFMA16(a, b, c) __builtin_amdgcn_mfma_f32_16x16x32_bf16((a), (b), (c), 0, 0, 0)

#define W1F_ELEMS (25 * 20 * 64 * 8)  // 256000  (K=800, N=320)
#define W2F_ELEMS (10 * 20 * 64 * 8)  // 102400  (K=320, N=320)
#define W3F_ELEMS (10 * 1 * 64 * 8)   // 5120    (K=320, N=16)
#define H1_OFF    768000              // byte offset of h1 in ws (256-aligned)
#define H1_BYTES  ((size_t)32768 * 320 * 2)

// ---------------------------------------------------------------------------
__global__ void prep_weights(const float* __restrict__ conv_w,
                             const float* __restrict__ W1,
                             const float* __restrict__ W2,
                             const float* __restrict__ W3,
                             bf16_t* __restrict__ W1f,
                             bf16_t* __restrict__ W2f,
                             bf16_t* __restrict__ W3f) {
    int idx = blockIdx.x * 256 + threadIdx.x;
    if (idx < 800 * 320) {
        int k = idx / 320;
        int n = idx - k * 320;
        float v = 0.0f;
        if (k < 784 && n < 300) {
            int py = k / 28;
            int px = k - py * 28;
#pragma unroll
            for (int ky = 0; ky < 3; ++ky) {
                int oy = py - ky;
                if (oy < 0 || oy > 25) continue;
#pragma unroll
                for (int kx = 0; kx < 3; ++kx) {
                    int ox = px - kx;
                    if (ox < 0 || ox > 25) continue;
                    v += conv_w[ky * 3 + kx] * W1[(oy * 26 + ox) * 300 + n];
                }
            }
        }
        int kc = k >> 5, quad = (k >> 3) & 3, j = k & 7;
        int nt = n >> 4, nin = n & 15;
        W1f[(((kc * 20 + nt) * 64 + quad * 16 + nin) << 3) + j] = (bf16_t)v;
    } else if (idx < 800 * 320 + 320 * 320) {
        int i2 = idx - 800 * 320;
        int k = i2 / 320;
        int n = i2 - k * 320;
        float v = (k < 300 && n < 300) ? W2[k * 300 + n] : 0.0f;
        int kc = k >> 5, quad = (k >> 3) & 3, j = k & 7;
        int nt = n >> 4, nin = n & 15;
        W2f[(((kc * 20 + nt) * 64 + quad * 16 + nin) << 3) + j] = (bf16_t)v;
    } else if (idx < 800 * 320 + 320 * 320 + 320 * 16) {
        int i3 = idx - (800 * 320 + 320 * 320);
        int k = i3 / 16;
        int n = i3 - k * 16;
        float v = (k < 300 && n < 10) ? W3[k * 10 + n] : 0.0f;
        int kc = k >> 5, quad = (k >> 3) & 3, j = k & 7;
        W3f[(((kc * 64) + quad * 16 + n) << 3) + j] = (bf16_t)v;
    }
}

// ---------------------------------------------------------------------------
// K1: h1 = relu(x @ W1eff + b1) -> bf16 row-major [32768][320].
// 256 thr = 4 waves; wave (mg=w&1, ng=w>>1): rows mg*32..+31, n-tiles
// ng*10..+9. No LDS, no barriers. Register dbuf for A (fp32) and B (frags).
// ---------------------------------------------------------------------------
__global__ __launch_bounds__(256, 2) void gemm1(
    const float* __restrict__ x, const float* __restrict__ b1,
    const bf16x8* __restrict__ W1f, bf16_t* __restrict__ h1) {
    const int tid = threadIdx.x;
    const int w   = tid >> 6;
    const int l   = tid & 63;
    const int mg  = w & 1;
    const int ng  = w >> 1;
    const int q   = l >> 4;
    const int l15 = l & 15;
    const int r0  = blockIdx.x * 64;

    const float* rowA = x + (size_t)(r0 + mg * 32 + l15) * 784;
    const float* rowB = rowA + 16 * 784;
    const bf16x8* wbase = W1f + ng * 10 * 64 + l;

    float4 abuf[2][4];
    bf16x8 bbuf[2][10];
    f32x4  acc[2][10];
#pragma unroll
    for (int m = 0; m < 2; ++m)
#pragma unroll
        for (int nt = 0; nt < 10; ++nt) acc[m][nt] = (f32x4){0.f, 0.f, 0.f, 0.f};

    // chunk 0 loads
    {
        const float4* pa = (const float4*)(rowA + q * 8);
        const float4* pb = (const float4*)(rowB + q * 8);
        abuf[0][0] = pa[0]; abuf[0][1] = pa[1];
        abuf[0][2] = pb[0]; abuf[0][3] = pb[1];
#pragma unroll
        for (int nt = 0; nt < 10; ++nt) bbuf[0][nt] = wbase[nt * 64];
    }

#pragma unroll
    for (int kc = 0; kc < 25; ++kc) {
        const int cur = kc & 1, nxt = cur ^ 1;

        // issue next-chunk loads first; they stay in flight over the MFMAs
        if (kc < 24) {
            int k0 = (kc + 1) * 32 + q * 8;
            if (k0 < 784) {
                const float4* pa = (const float4*)(rowA + k0);
                const float4* pb = (const float4*)(rowB + k0);
                abuf[nxt][0] = pa[0]; abuf[nxt][1] = pa[1];
                abuf[nxt][2] = pb[0]; abuf[nxt][3] = pb[1];
            } else {
                abuf[nxt][0] = abuf[nxt][1] = abuf[nxt][2] = abuf[nxt][3] =
                    make_float4(0.f, 0.f, 0.f, 0.f);
            }
            const bf16x8* wb = wbase + (kc + 1) * 20 * 64;
#pragma unroll
            for (int nt = 0; nt < 10; ++nt) bbuf[nxt][nt] = wb[nt * 64];
        }

        bf16x8 afA, afB;
        afA[0] = (bf16_t)abuf[cur][0].x; afA[1] = (bf16_t)abuf[cur][0].y;
        afA[2] = (bf16_t)abuf[cur][0].z; afA[3] = (bf16_t)abuf[cur][0].w;
        afA[4] = (bf16_t)abuf[cur][1].x; afA[5] = (bf16_t)abuf[cur][1].y;
        afA[6] = (bf16_t)abuf[cur][1].z; afA[7] = (bf16_t)abuf[cur][1].w;
        afB[0] = (bf16_t)abuf[cur][2].x; afB[1] = (bf16_t)abuf[cur][2].y;
        afB[2] = (bf16_t)abuf[cur][2].z; afB[3] = (bf16_t)abuf[cur][2].w;
        afB[4] = (bf16_t)abuf[cur][3].x; afB[5] = (bf16_t)abuf[cur][3].y;
        afB[6] = (bf16_t)abuf[cur][3].z; afB[7] = (bf16_t)abuf[cur][3].w;

#pragma unroll
        for (int nt = 0; nt < 10; ++nt) {
            acc[0][nt] = MFMA16(afA, bbuf[cur][nt], acc[0][nt]);
            acc[1][nt] = MFMA16(afB, bbuf[cur][nt], acc[1][nt]);
        }
    }

    // epilogue: bias + relu -> h1 bf16 row-major
#pragma unroll
    for (int nt = 0; nt < 10; ++nt) {
        int n = (ng * 10 + nt) * 16 + l15;
        float bias = (n < 300) ? b1[n] : 0.0f;
#pragma unroll
        for (int mt2 = 0; mt2 < 2; ++mt2) {
            int row_base = r0 + (mg * 2 + mt2) * 16 + q * 4;
#pragma unroll
            for (int r = 0; r < 4; ++r) {
                float v = acc[mt2][nt][r] + bias;
                v = v > 0.f ? v : 0.f;
                h1[(size_t)(row_base + r) * 320 + n] = (bf16_t)v;
            }
        }
    }
}

// ---------------------------------------------------------------------------
// K2: out = relu(h1 @ W2 + b2) @ W3 + b3. Same wave mapping as K1.
// A-frags load straight from bf16 h1 rows. Barrier-free GEMM2 K-loop; one
// barrier for the h2 C->A exchange; GEMM3 per-wave.
// ---------------------------------------------------------------------------
__global__ __launch_bounds__(256, 2) void gemm23(
    const bf16_t* __restrict__ h1, const float* __restrict__ b2,
    const float* __restrict__ b3, const bf16x8* __restrict__ W2f,
    const bf16x8* __restrict__ W3f, float* __restrict__ out) {
    __shared__ bf16x8 hx[10 * 4 * 64];  // 40KB: h2 in A-frag order

    const int tid = threadIdx.x;
    const int w   = tid >> 6;
    const int l   = tid & 63;
    const int mg  = w & 1;
    const int ng  = w >> 1;
    const int q   = l >> 4;
    const int l15 = l & 15;
    const int r0  = blockIdx.x * 64;

    const bf16_t* rowA = h1 + (size_t)(r0 + mg * 32 + l15) * 320;
    const bf16_t* rowB = rowA + 16 * 320;
    const bf16x8* wbase = W2f + ng * 10 * 64 + l;

    bf16x8 adbuf[2][2];
    bf16x8 bbuf[2][10];
    f32x4  acc[2][10];
#pragma unroll
    for (int m = 0; m < 2; ++m)
#pragma unroll
        for (int nt = 0; nt < 10; ++nt) acc[m][nt] = (f32x4){0.f, 0.f, 0.f, 0.f};

    adbuf[0][0] = *(const bf16x8*)(rowA + q * 8);
    adbuf[0][1] = *(const bf16x8*)(rowB + q * 8);
#pragma unroll
    for (int nt = 0; nt < 10; ++nt) bbuf[0][nt] = wbase[nt * 64];

#pragma unroll
    for (int kc = 0; kc < 10; ++kc) {
        const int cur = kc & 1, nxt = cur ^ 1;
        if (kc < 9) {
            int k0 = (kc + 1) * 32 + q * 8;
            adbuf[nxt][0] = *(const bf16x8*)(rowA + k0);
            adbuf[nxt][1] = *(const bf16x8*)(rowB + k0);
            const bf16x8* wb = wbase + (kc + 1) * 20 * 64;
#pragma unroll
            for (int nt = 0; nt < 10; ++nt) bbuf[nxt][nt] = wb[nt * 64];
        }
#pragma unroll
        for (int nt = 0; nt < 10; ++nt) {
            acc[0][nt] = MFMA16(adbuf[cur][0], bbuf[cur][nt], acc[0][nt]);
            acc[1][nt] = MFMA16(adbuf[cur][1], bbuf[cur][nt], acc[1][nt]);
        }
    }

    // h2 = relu(acc + b2) -> LDS in A-frag order [kc2][mt][64][8]
    {
        bf16_t* hb = (bf16_t*)hx;
#pragma unroll
        for (int nt = 0; nt < 10; ++nt) {
            int n = (ng * 10 + nt) * 16 + l15;
            float bias = (n < 300) ? b2[n] : 0.0f;
            int kc2 = n >> 5, quad = (n >> 3) & 3, j = n & 7;
#pragma unroll
            for (int mt2 = 0; mt2 < 2; ++mt2) {
                int mt = mg * 2 + mt2;
#pragma unroll
                for (int r = 0; r < 4; ++r) {
                    float v = acc[mt2][nt][r] + bias;
                    v = v > 0.f ? v : 0.f;
                    hb[(((kc2 * 4 + mt) * 64 + quad * 16 + q * 4 + r) << 3) + j] =
                        (bf16_t)v;
                }
            }
        }
    }
    __syncthreads();

    // GEMM3: wave w -> m-tile w; W3 B-frags from global (L2-hot, 5KB)
    f32x4 acc3 = (f32x4){0.f, 0.f, 0.f, 0.f};
#pragma unroll
    for (int kc = 0; kc < 10; ++kc)
        acc3 = MFMA16(hx[(kc * 4 + w) * 64 + l], W3f[kc * 64 + l], acc3);
    if (l15 < 10) {
        float bias = b3[l15];
#pragma unroll
        for (int r = 0; r < 4; ++r)
            out[(size_t)(r0 + w * 16 + q * 4 + r) * 10 + l15] = acc3[r] + bias;
    }
}

// ---------------------------------------------------------------------------
extern "C" void kernel_launch(void* const* d_in, const int* in_sizes, int n_in,
                              void* d_out, int out_size, void* d_ws, size_t ws_size,
                              hipStream_t stream) {
    const float* x      = (const float*)d_in[0];
    const float* conv_w = (const float*)d_in[1];
    const float* W1     = (const float*)d_in[2];
    const float* b1     = (const float*)d_in[3];
    const float* W2     = (const float*)d_in[4];
    const float* b2     = (const float*)d_in[5];
    const float* W3     = (const float*)d_in[6];
    const float* b3     = (const float*)d_in[7];
    float* out = (float*)d_out;

    char* ws = (char*)d_ws;
    bf16_t* W1f = (bf16_t*)(ws);
    bf16_t* W2f = (bf16_t*)(ws + (size_t)W1F_ELEMS * 2);
    bf16_t* W3f = (bf16_t*)(ws + (size_t)(W1F_ELEMS + W2F_ELEMS) * 2);
    bf16_t* h1  = (bf16_t*)(ws + H1_OFF);
    if (ws_size < H1_OFF + H1_BYTES) return;  // need ~21.7 MB scratch

    int prep_total = 800 * 320 + 320 * 320 + 320 * 16;  // 363520
    prep_weights<<<(prep_total + 255) / 256, 256, 0, stream>>>(
        conv_w, W1, W2, W3, W1f, W2f, W3f);

    gemm1<<<32768 / 64, 256, 0, stream>>>(x, b1, (const bf16x8*)W1f, h1);

    gemm23<<<32768 / 64, 256, 0, stream>>>(
        h1, b2, b3, (const bf16x8*)W2f, (const bf16x8*)W3f, out);
}

// Round 5
// 198.135 us; speedup vs baseline: 1.1738x; 1.1738x over previous
//
#include <hip/hip_runtime.h>

// ---------------------------------------------------------------------------
// DigitConvolutionalModel: x(32768,784) -> conv3x3(valid) -> 676
//   -> relu(@W1(676,300)+b1) -> relu(@W2(300,300)+b2) -> @W3(300,10)+b3
//
// R5: gemm1 reads x in ADDRESS-SEQUENTIAL order (512B runs per instruction)
// into an LDS A-buffer, fixing the ~1TB/s DRAM-efficiency ceiling that bound
// R1-R4 (column-major 64B-fragment walk over x). A-frags come from LDS;
// B keeps the R3 stage16 double-buffer. gemm23/prep = R3 verbatim.
// ---------------------------------------------------------------------------

typedef __bf16 bf16_t;
typedef __bf16 bf16x4 __attribute__((ext_vector_type(4)));
typedef __bf16 bf16x8 __attribute__((ext_vector_type(8)));
typedef float  f32x4  __attribute__((ext_vector_type(4)));

#define MFMA16(a, b, c) __builtin_amdgcn_mfma_f32_16x16x32_bf16((a), (b), (c), 0, 0, 0)

#define W1F_ELEMS (25 * 20 * 64 * 8)  // 256000  (K=800, N=320)
#define W2F_ELEMS (10 * 20 * 64 * 8)  // 102400  (K=320, N=320)
#define W3F_ELEMS (10 * 1 * 64 * 8)   // 5120    (K=320, N=16)
#define H1_OFF    768000              // byte offset of h1 in ws (256-aligned)
#define H1_BYTES  ((size_t)32768 * 320 * 2)
#define ASTRIDE   136                 // bf16 row stride in Abuf (272B, 16B mult)

// ---------------------------------------------------------------------------
__global__ void prep_weights(const float* __restrict__ conv_w,
                             const float* __restrict__ W1,
                             const float* __restrict__ W2,
                             const float* __restrict__ W3,
                             bf16_t* __restrict__ W1f,
                             bf16_t* __restrict__ W2f,
                             bf16_t* __restrict__ W3f) {
    int idx = blockIdx.x * 256 + threadIdx.x;
    if (idx < 800 * 320) {
        int k = idx / 320;
        int n = idx - k * 320;
        float v = 0.0f;
        if (k < 784 && n < 300) {
            int py = k / 28;
            int px = k - py * 28;
#pragma unroll
            for (int ky = 0; ky < 3; ++ky) {
                int oy = py - ky;
                if (oy < 0 || oy > 25) continue;
#pragma unroll
                for (int kx = 0; kx < 3; ++kx) {
                    int ox = px - kx;
                    if (ox < 0 || ox > 25) continue;
                    v += conv_w[ky * 3 + kx] * W1[(oy * 26 + ox) * 300 + n];
                }
            }
        }
        int kc = k >> 5, quad = (k >> 3) & 3, j = k & 7;
        int nt = n >> 4, nin = n & 15;
        W1f[(((kc * 20 + nt) * 64 + quad * 16 + nin) << 3) + j] = (bf16_t)v;
    } else if (idx < 800 * 320 + 320 * 320) {
        int i2 = idx - 800 * 320;
        int k = i2 / 320;
        int n = i2 - k * 320;
        float v = (k < 300 && n < 300) ? W2[k * 300 + n] : 0.0f;
        int kc = k >> 5, quad = (k >> 3) & 3, j = k & 7;
        int nt = n >> 4, nin = n & 15;
        W2f[(((kc * 20 + nt) * 64 + quad * 16 + nin) << 3) + j] = (bf16_t)v;
    } else if (idx < 800 * 320 + 320 * 320 + 320 * 16) {
        int i3 = idx - (800 * 320 + 320 * 320);
        int k = i3 / 16;
        int n = i3 - k * 16;
        float v = (k < 300 && n < 10) ? W3[k * 10 + n] : 0.0f;
        int kc = k >> 5, quad = (k >> 3) & 3, j = k & 7;
        W3f[(((kc * 64) + quad * 16 + n) << 3) + j] = (bf16_t)v;
    }
}

// async global -> LDS, 16B/lane; lds base wave-uniform.
__device__ __forceinline__ void stage16(const bf16x8* g, bf16x8* l) {
    __builtin_amdgcn_global_load_lds(
        (const __attribute__((address_space(1))) void*)g,
        (__attribute__((address_space(3))) void*)l, 16, 0, 0);
}

// ---------------------------------------------------------------------------
// K1: h1 = relu(x @ W1eff + b1) -> bf16 row-major [32768][320].
// 64 rows/block, 512 thr = 8 waves; wave (mh=w&1, nq=w>>1): rows mh*32..+31
// (2 m-tiles), n-tiles nq*5..+4.
// x staged in 7 bands of 128 cols (last band 32): per instruction, lanes
// read 2 rows x 512B CONTIGUOUS -> DRAM-efficient. fp32->bf16 into Abuf.
// B: stage16 double-buffer (R3). One barrier per chunk + 1 per band.
// ---------------------------------------------------------------------------
__global__ __launch_bounds__(512, 4) void gemm1(
    const float* __restrict__ x, const float* __restrict__ b1,
    const bf16x8* __restrict__ W1f, bf16_t* __restrict__ h1) {
    __shared__ bf16x8 bufB[2 * 1280];          // 40 KB: B double buffer
    __shared__ bf16_t Abuf[64 * ASTRIDE];      // 17 KB: one A band (64 x 128)

    const int tid = threadIdx.x;
    const int w   = tid >> 6;
    const int l   = tid & 63;
    const int mh  = w & 1;
    const int nq  = w >> 1;
    const int q   = l >> 4;
    const int l15 = l & 15;
    const int r0  = blockIdx.x * 64;

    // sequential-stage maps (bands 0-5): idx = i*512+tid -> row idx>>5, col4 idx&31
    const int srow = tid >> 5;   // 0..15 (+ i*16)
    const int sc4  = tid & 31;   // float4-col within band
    // band 6 map: 64 rows x 8 float4 (only first 4 valid)
    const int trow = tid >> 3;
    const int tc4  = tid & 7;

    // prologue: stage B chunk 0; prefetch A band 0
    for (int t = w; t < 20; t += 8) stage16(W1f + (t * 64 + l), bufB + t * 64);

    float4 pf[4];
#pragma unroll
    for (int i = 0; i < 4; ++i)
        pf[i] = *(const float4*)(x + (size_t)(r0 + i * 16 + srow) * 784 + sc4 * 4);

    f32x4 acc[2][5];
#pragma unroll
    for (int m = 0; m < 2; ++m)
#pragma unroll
        for (int nt = 0; nt < 5; ++nt) acc[m][nt] = (f32x4){0.f, 0.f, 0.f, 0.f};

    int kc = 0;
    for (int band = 0; band < 7; ++band) {
        __syncthreads();  // (a) prev band A-reads + prev chunk B-reads done

        // write prefetched band to Abuf (fp32 -> bf16)
        if (band < 6) {
#pragma unroll
            for (int i = 0; i < 4; ++i) {
                bf16x4 v;
                v[0] = (bf16_t)pf[i].x; v[1] = (bf16_t)pf[i].y;
                v[2] = (bf16_t)pf[i].z; v[3] = (bf16_t)pf[i].w;
                *(bf16x4*)&Abuf[(i * 16 + srow) * ASTRIDE + sc4 * 4] = v;
            }
        } else {
            bf16x4 v;
            v[0] = (bf16_t)pf[0].x; v[1] = (bf16_t)pf[0].y;
            v[2] = (bf16_t)pf[0].z; v[3] = (bf16_t)pf[0].w;
            *(bf16x4*)&Abuf[trow * ASTRIDE + tc4 * 4] = v;
        }

        // prefetch next band (sequential 512B runs)
        if (band + 1 < 6) {
#pragma unroll
            for (int i = 0; i < 4; ++i)
                pf[i] = *(const float4*)(x + (size_t)(r0 + i * 16 + srow) * 784 +
                                         (band + 1) * 128 + sc4 * 4);
        } else if (band + 1 == 6) {
            pf[0] = (tc4 < 4)
                ? *(const float4*)(x + (size_t)(r0 + trow) * 784 + 768 + tc4 * 4)
                : make_float4(0.f, 0.f, 0.f, 0.f);
        }

        const int nch = (band < 6) ? 4 : 1;
        for (int kcl = 0; kcl < nch; ++kcl, ++kc) {
            __syncthreads();  // (b)/chunk-top: Abuf + staged B visible

            if (kc + 1 < 25) {
                int s1 = (kc + 1) & 1;
                for (int t = w; t < 20; t += 8)
                    stage16(W1f + (((kc + 1) * 20 + t) * 64 + l),
                            bufB + s1 * 1280 + t * 64);
            }

            bf16x8 afA = *(const bf16x8*)&Abuf[(mh * 32 + l15) * ASTRIDE +
                                               kcl * 32 + q * 8];
            bf16x8 afB = *(const bf16x8*)&Abuf[(mh * 32 + 16 + l15) * ASTRIDE +
                                               kcl * 32 + q * 8];
            const bf16x8* bb = bufB + (kc & 1) * 1280 + (nq * 5) * 64 + l;
#pragma unroll
            for (int nt = 0; nt < 5; ++nt) {
                bf16x8 b = bb[nt * 64];
                acc[0][nt] = MFMA16(afA, b, acc[0][nt]);
                acc[1][nt] = MFMA16(afB, b, acc[1][nt]);
            }
        }
    }

    // epilogue: bias + relu -> h1 bf16 row-major
#pragma unroll
    for (int nt = 0; nt < 5; ++nt) {
        int n = (nq * 5 + nt) * 16 + l15;
        float bias = (n < 300) ? b1[n] : 0.0f;
#pragma unroll
        for (int mt2 = 0; mt2 < 2; ++mt2) {
            int mt = mh * 2 + mt2;
#pragma unroll
            for (int r = 0; r < 4; ++r) {
                float v = acc[mt2][nt][r] + bias;
                v = v > 0.f ? v : 0.f;
                h1[(size_t)(r0 + mt * 16 + q * 4 + r) * 320 + n] = (bf16_t)v;
            }
        }
    }
}

// ---------------------------------------------------------------------------
// K2: out = relu(h1 @ W2 + b2) @ W3 + b3.  (R3 version, unchanged)
// ---------------------------------------------------------------------------
__global__ __launch_bounds__(512, 4) void gemm23(
    const bf16_t* __restrict__ h1, const float* __restrict__ b2,
    const float* __restrict__ b3, const bf16x8* __restrict__ W2f,
    const bf16x8* __restrict__ W3f, float* __restrict__ out) {
    __shared__ bf16x8 arena[2560];  // 40KB: B2 dbuf -> h2 exchange

    const int tid = threadIdx.x;
    const int w   = tid >> 6;
    const int l   = tid & 63;
    const int mh  = w & 1;
    const int nq  = w >> 1;
    const int q   = l >> 4;
    const int l15 = l & 15;
    const int r0  = blockIdx.x * 64;

    const bf16_t* rowA = h1 + (size_t)(r0 + mh * 32 + l15) * 320;
    const bf16_t* rowB = rowA + 16 * 320;

    for (int t = w; t < 20; t += 8) stage16(W2f + (t * 64 + l), arena + t * 64);
    bf16x8 uaA = *(const bf16x8*)(rowA + q * 8);
    bf16x8 uaB = *(const bf16x8*)(rowB + q * 8);

    f32x4 acc[2][5];
#pragma unroll
    for (int m = 0; m < 2; ++m)
#pragma unroll
        for (int nt = 0; nt < 5; ++nt) acc[m][nt] = (f32x4){0.f, 0.f, 0.f, 0.f};

    for (int kc = 0; kc < 10; ++kc) {
        __syncthreads();

        if (kc + 1 < 10) {
            int s1 = (kc + 1) & 1;
            for (int t = w; t < 20; t += 8)
                stage16(W2f + (((kc + 1) * 20 + t) * 64 + l),
                        arena + s1 * 1280 + t * 64);
        }

        bf16x8 afA = uaA, afB = uaB;
        if (kc + 1 < 10) {
            uaA = *(const bf16x8*)(rowA + (kc + 1) * 32 + q * 8);
            uaB = *(const bf16x8*)(rowB + (kc + 1) * 32 + q * 8);
        }

        const bf16x8* bb = arena + (kc & 1) * 1280 + (nq * 5) * 64 + l;
#pragma unroll
        for (int nt = 0; nt < 5; ++nt) {
            bf16x8 b = bb[nt * 64];
            acc[0][nt] = MFMA16(afA, b, acc[0][nt]);
            acc[1][nt] = MFMA16(afB, b, acc[1][nt]);
        }
    }
    __syncthreads();  // done reading arena (B2)

    // h2 = relu(acc + b2) -> arena as A-frags [kc2][mt][64][8]
    {
        bf16_t* hb = (bf16_t*)arena;
#pragma unroll
        for (int nt = 0; nt < 5; ++nt) {
            int n = (nq * 5 + nt) * 16 + l15;
            float bias = (n < 300) ? b2[n] : 0.0f;
            int kc2 = n >> 5, quad = (n >> 3) & 3, j = n & 7;
#pragma unroll
            for (int mt2 = 0; mt2 < 2; ++mt2) {
                int mt = mh * 2 + mt2;
#pragma unroll
                for (int r = 0; r < 4; ++r) {
                    float v = acc[mt2][nt][r] + bias;
                    v = v > 0.f ? v : 0.f;
                    hb[(((kc2 * 4 + mt) * 64 + quad * 16 + q * 4 + r) << 3) + j] =
                        (bf16_t)v;
                }
            }
        }
    }
    __syncthreads();

    // GEMM3: waves 0-3 (mt = w), W3 B-frags straight from global (L2-hot)
    if (w < 4) {
        f32x4 acc3 = (f32x4){0.f, 0.f, 0.f, 0.f};
        for (int kc = 0; kc < 10; ++kc) {
            bf16x8 a = arena[(kc * 4 + w) * 64 + l];
            bf16x8 b = W3f[kc * 64 + l];
            acc3 = MFMA16(a, b, acc3);
        }
        if (l15 < 10) {
            float bias = b3[l15];
#pragma unroll
            for (int r = 0; r < 4; ++r)
                out[(size_t)(r0 + w * 16 + q * 4 + r) * 10 + l15] = acc3[r] + bias;
        }
    }
}

// ---------------------------------------------------------------------------
extern "C" void kernel_launch(void* const* d_in, const int* in_sizes, int n_in,
                              void* d_out, int out_size, void* d_ws, size_t ws_size,
                              hipStream_t stream) {
    const float* x      = (const float*)d_in[0];
    const float* conv_w = (const float*)d_in[1];
    const float* W1     = (const float*)d_in[2];
    const float* b1     = (const float*)d_in[3];
    const float* W2     = (const float*)d_in[4];
    const float* b2     = (const float*)d_in[5];
    const float* W3     = (const float*)d_in[6];
    const float* b3     = (const float*)d_in[7];
    float* out = (float*)d_out;

    char* ws = (char*)d_ws;
    bf16_t* W1f = (bf16_t*)(ws);
    bf16_t* W2f = (bf16_t*)(ws + (size_t)W1F_ELEMS * 2);
    bf16_t* W3f = (bf16_t*)(ws + (size_t)(W1F_ELEMS + W2F_ELEMS) * 2);
    bf16_t* h1  = (bf16_t*)(ws + H1_OFF);
    if (ws_size < H1_OFF + H1_BYTES) return;  // need ~21.7 MB scratch

    int prep_total = 800 * 320 + 320 * 320 + 320 * 16;  // 363520
    prep_weights<<<(prep_total + 255) / 256, 256, 0, stream>>>(
        conv_w, W1, W2, W3, W1f, W2f, W3f);

    gemm1<<<32768 / 64, 512, 0, stream>>>(x, b1, (const bf16x8*)W1f, h1);

    gemm23<<<32768 / 64, 512, 0, stream>>>(
        h1, b2, b3, (const bf16x8*)W2f, (const bf16x8*)W3f, out);
}

// Round 6
// 187.545 us; speedup vs baseline: 1.2401x; 1.0565x over previous
//
#include <hip/hip_runtime.h>

// ---------------------------------------------------------------------------
// DigitConvolutionalModel: x(32768,784) -> conv3x3(valid) -> 676
//   -> relu(@W1(676,300)+b1) -> relu(@W2(300,300)+b2) -> @W3(300,10)+b3
//
// R6 = R5 gemm1 (sequential-order x staging, the R5 win) fused with the R2
// in-LDS tail (GEMM2+3 on h kept in LDS; h1 never touches global).
//  - conv folded into W1eff (K 784->800, N 300->320), bf16 B-frag order.
//  - 512 blocks x 64 rows, 512 thr = 8 waves; wave (mh=w&1, nq=w>>1).
//  - LDS 77KB: [B1 dbuf 40KB | Abuf 17KB | B2 20KB]; hbuf overlays B1 dbuf
//    after GEMM1. 2 blocks/CU.
// ---------------------------------------------------------------------------

typedef __bf16 bf16_t;
typedef __bf16 bf16x4 __attribute__((ext_vector_type(4)));
typedef __bf16 bf16x8 __attribute__((ext_vector_type(8)));
typedef float  f32x4  __attribute__((ext_vector_type(4)));

#define MFMA16(a, b, c) __builtin_amdgcn_mfma_f32_16x16x32_bf16((a), (b), (c), 0, 0, 0)

#define W1F_ELEMS (25 * 20 * 64 * 8)  // 256000  (K=800, N=320)
#define W2F_ELEMS (10 * 20 * 64 * 8)  // 102400  (K=320, N=320)
#define W3F_ELEMS (10 * 1 * 64 * 8)   // 5120    (K=320, N=16)
#define ASTRIDE   136                 // bf16 row stride in Abuf (272B)

// ---------------------------------------------------------------------------
__global__ void prep_weights(const float* __restrict__ conv_w,
                             const float* __restrict__ W1,
                             const float* __restrict__ W2,
                             const float* __restrict__ W3,
                             bf16_t* __restrict__ W1f,
                             bf16_t* __restrict__ W2f,
                             bf16_t* __restrict__ W3f) {
    int idx = blockIdx.x * 256 + threadIdx.x;
    if (idx < 800 * 320) {
        int k = idx / 320;
        int n = idx - k * 320;
        float v = 0.0f;
        if (k < 784 && n < 300) {
            int py = k / 28;
            int px = k - py * 28;
#pragma unroll
            for (int ky = 0; ky < 3; ++ky) {
                int oy = py - ky;
                if (oy < 0 || oy > 25) continue;
#pragma unroll
                for (int kx = 0; kx < 3; ++kx) {
                    int ox = px - kx;
                    if (ox < 0 || ox > 25) continue;
                    v += conv_w[ky * 3 + kx] * W1[(oy * 26 + ox) * 300 + n];
                }
            }
        }
        int kc = k >> 5, quad = (k >> 3) & 3, j = k & 7;
        int nt = n >> 4, nin = n & 15;
        W1f[(((kc * 20 + nt) * 64 + quad * 16 + nin) << 3) + j] = (bf16_t)v;
    } else if (idx < 800 * 320 + 320 * 320) {
        int i2 = idx - 800 * 320;
        int k = i2 / 320;
        int n = i2 - k * 320;
        float v = (k < 300 && n < 300) ? W2[k * 300 + n] : 0.0f;
        int kc = k >> 5, quad = (k >> 3) & 3, j = k & 7;
        int nt = n >> 4, nin = n & 15;
        W2f[(((kc * 20 + nt) * 64 + quad * 16 + nin) << 3) + j] = (bf16_t)v;
    } else if (idx < 800 * 320 + 320 * 320 + 320 * 16) {
        int i3 = idx - (800 * 320 + 320 * 320);
        int k = i3 / 16;
        int n = i3 - k * 16;
        float v = (k < 300 && n < 10) ? W3[k * 10 + n] : 0.0f;
        int kc = k >> 5, quad = (k >> 3) & 3, j = k & 7;
        W3f[(((kc * 64) + quad * 16 + n) << 3) + j] = (bf16_t)v;
    }
}

// async global -> LDS, 16B/lane; lds base wave-uniform.
__device__ __forceinline__ void stage16(const bf16x8* g, bf16x8* l) {
    __builtin_amdgcn_global_load_lds(
        (const __attribute__((address_space(1))) void*)g,
        (__attribute__((address_space(3))) void*)l, 16, 0, 0);
}

// ---------------------------------------------------------------------------
// Fused: out = relu(relu(x@W1eff+b1)@W2+b2)@W3+b3.
// GEMM1: x staged in 7 bands of 128 cols, lanes read 512B CONTIGUOUS runs
// (the R5 DRAM-order fix); fp32->bf16 into Abuf; B1 stage16 double-buffer.
// Tail: h1 -> LDS (A-frag order, overlays B1 dbuf); GEMM2 with B2 staged
// single-buffer; h2 -> LDS; GEMM3 with W3 frags from global (L2-hot).
// ---------------------------------------------------------------------------
__global__ __launch_bounds__(512, 4) void fused_mlp(
    const float* __restrict__ x, const float* __restrict__ b1,
    const float* __restrict__ b2, const float* __restrict__ b3,
    const bf16x8* __restrict__ W1f, const bf16x8* __restrict__ W2f,
    const bf16x8* __restrict__ W3f, float* __restrict__ out) {
    __shared__ bf16x8 bufB1[2 * 1280];     // 40 KB: B1 dbuf; later hbuf
    __shared__ bf16_t Abuf[64 * ASTRIDE];  // 17 KB: one A band (64 x 128)
    __shared__ bf16x8 bufB2[1280];         // 20 KB: B2 single buffer

    bf16x8* hbuf = bufB1;  // [10][4][64] A-frag order after GEMM1

    const int tid = threadIdx.x;
    const int w   = tid >> 6;
    const int l   = tid & 63;
    const int mh  = w & 1;
    const int nq  = w >> 1;
    const int q   = l >> 4;
    const int l15 = l & 15;
    const int r0  = blockIdx.x * 64;

    // sequential-stage maps (bands 0-5): row = i*16 + (tid>>5), col4 = tid&31
    const int srow = tid >> 5;
    const int sc4  = tid & 31;
    // band-6 map: 64 rows x 8 float4 (first 4 valid)
    const int trow = tid >> 3;
    const int tc4  = tid & 7;

    // prologue: stage B1 chunk 0 and B2 chunk 0; prefetch A band 0
    for (int t = w; t < 20; t += 8) stage16(W1f + (t * 64 + l), bufB1 + t * 64);
    for (int t = w; t < 20; t += 8) stage16(W2f + (t * 64 + l), bufB2 + t * 64);

    float4 pf[4];
#pragma unroll
    for (int i = 0; i < 4; ++i)
        pf[i] = *(const float4*)(x + (size_t)(r0 + i * 16 + srow) * 784 + sc4 * 4);

    f32x4 acc[2][5];
#pragma unroll
    for (int m = 0; m < 2; ++m)
#pragma unroll
        for (int nt = 0; nt < 5; ++nt) acc[m][nt] = (f32x4){0.f, 0.f, 0.f, 0.f};

    // ---------------- GEMM1 ------------------------------------------------
    int kc = 0;
    for (int band = 0; band < 7; ++band) {
        __syncthreads();  // prev band A-reads + prev chunk B-reads done

        if (band < 6) {
#pragma unroll
            for (int i = 0; i < 4; ++i) {
                bf16x4 v;
                v[0] = (bf16_t)pf[i].x; v[1] = (bf16_t)pf[i].y;
                v[2] = (bf16_t)pf[i].z; v[3] = (bf16_t)pf[i].w;
                *(bf16x4*)&Abuf[(i * 16 + srow) * ASTRIDE + sc4 * 4] = v;
            }
        } else {
            bf16x4 v;
            v[0] = (bf16_t)pf[0].x; v[1] = (bf16_t)pf[0].y;
            v[2] = (bf16_t)pf[0].z; v[3] = (bf16_t)pf[0].w;
            *(bf16x4*)&Abuf[trow * ASTRIDE + tc4 * 4] = v;
        }

        if (band + 1 < 6) {
#pragma unroll
            for (int i = 0; i < 4; ++i)
                pf[i] = *(const float4*)(x + (size_t)(r0 + i * 16 + srow) * 784 +
                                         (band + 1) * 128 + sc4 * 4);
        } else if (band + 1 == 6) {
            pf[0] = (tc4 < 4)
                ? *(const float4*)(x + (size_t)(r0 + trow) * 784 + 768 + tc4 * 4)
                : make_float4(0.f, 0.f, 0.f, 0.f);
        }

        const int nch = (band < 6) ? 4 : 1;
        for (int kcl = 0; kcl < nch; ++kcl, ++kc) {
            __syncthreads();  // Abuf + staged B1 visible

            if (kc + 1 < 25) {
                int s1 = (kc + 1) & 1;
                for (int t = w; t < 20; t += 8)
                    stage16(W1f + (((kc + 1) * 20 + t) * 64 + l),
                            bufB1 + s1 * 1280 + t * 64);
            }

            bf16x8 afA = *(const bf16x8*)&Abuf[(mh * 32 + l15) * ASTRIDE +
                                               kcl * 32 + q * 8];
            bf16x8 afB = *(const bf16x8*)&Abuf[(mh * 32 + 16 + l15) * ASTRIDE +
                                               kcl * 32 + q * 8];
            const bf16x8* bb = bufB1 + (kc & 1) * 1280 + (nq * 5) * 64 + l;
#pragma unroll
            for (int nt = 0; nt < 5; ++nt) {
                bf16x8 b = bb[nt * 64];
                acc[0][nt] = MFMA16(afA, b, acc[0][nt]);
                acc[1][nt] = MFMA16(afB, b, acc[1][nt]);
            }
        }
    }
    __syncthreads();  // all waves done reading bufB1 before hbuf overwrite

    // ---------------- h1 = relu(C1+b1) -> hbuf (A-frag order) --------------
    {
        bf16_t* hb = (bf16_t*)hbuf;
#pragma unroll
        for (int nt = 0; nt < 5; ++nt) {
            int n = (nq * 5 + nt) * 16 + l15;
            float bias = (n < 300) ? b1[n] : 0.0f;
            int kc2 = n >> 5, quad = (n >> 3) & 3, j = n & 7;
#pragma unroll
            for (int mt2 = 0; mt2 < 2; ++mt2) {
                int mt = mh * 2 + mt2;
#pragma unroll
                for (int r = 0; r < 4; ++r) {
                    float v = acc[mt2][nt][r] + bias;
                    v = v > 0.f ? v : 0.f;
                    hb[(((kc2 * 4 + mt) * 64 + quad * 16 + q * 4 + r) << 3) + j] =
                        (bf16_t)v;
                }
            }
        }
    }
    __syncthreads();

    // ---------------- GEMM2: 10 chunks; B2 single-buffer staged ------------
#pragma unroll
    for (int m = 0; m < 2; ++m)
#pragma unroll
        for (int nt = 0; nt < 5; ++nt) acc[m][nt] = (f32x4){0.f, 0.f, 0.f, 0.f};
    for (int kc2 = 0; kc2 < 10; ++kc2) {
        bf16x8 a0 = hbuf[(kc2 * 4 + mh * 2 + 0) * 64 + l];
        bf16x8 a1 = hbuf[(kc2 * 4 + mh * 2 + 1) * 64 + l];
        const bf16x8* bb = bufB2 + (nq * 5) * 64 + l;
#pragma unroll
        for (int nt = 0; nt < 5; ++nt) {
            bf16x8 b = bb[nt * 64];
            acc[0][nt] = MFMA16(a0, b, acc[0][nt]);
            acc[1][nt] = MFMA16(a1, b, acc[1][nt]);
        }
        if (kc2 + 1 < 10) {
            __syncthreads();  // reads of chunk kc2 done
            for (int t = w; t < 20; t += 8)
                stage16(W2f + (((kc2 + 1) * 20 + t) * 64 + l), bufB2 + t * 64);
            __syncthreads();  // staged chunk kc2+1 visible
        }
    }
    __syncthreads();  // done reading hbuf(h1) before h2 overwrite

    // ---------------- h2 = relu(C2+b2) -> hbuf -----------------------------
    {
        bf16_t* hb = (bf16_t*)hbuf;
#pragma unroll
        for (int nt = 0; nt < 5; ++nt) {
            int n = (nq * 5 + nt) * 16 + l15;
            float bias = (n < 300) ? b2[n] : 0.0f;
            int kc2 = n >> 5, quad = (n >> 3) & 3, j = n & 7;
#pragma unroll
            for (int mt2 = 0; mt2 < 2; ++mt2) {
                int mt = mh * 2 + mt2;
#pragma unroll
                for (int r = 0; r < 4; ++r) {
                    float v = acc[mt2][nt][r] + bias;
                    v = v > 0.f ? v : 0.f;
                    hb[(((kc2 * 4 + mt) * 64 + quad * 16 + q * 4 + r) << 3) + j] =
                        (bf16_t)v;
                }
            }
        }
    }
    __syncthreads();

    // ---------------- GEMM3: waves 0-3 (mt=w); W3 frags from global --------
    if (w < 4) {
        f32x4 acc3 = (f32x4){0.f, 0.f, 0.f, 0.f};
#pragma unroll
        for (int kc3 = 0; kc3 < 10; ++kc3)
            acc3 = MFMA16(hbuf[(kc3 * 4 + w) * 64 + l], W3f[kc3 * 64 + l], acc3);
        if (l15 < 10) {
            float bias = b3[l15];
#pragma unroll
            for (int r = 0; r < 4; ++r)
                out[(size_t)(r0 + w * 16 + q * 4 + r) * 10 + l15] = acc3[r] + bias;
        }
    }
}

// ---------------------------------------------------------------------------
extern "C" void kernel_launch(void* const* d_in, const int* in_sizes, int n_in,
                              void* d_out, int out_size, void* d_ws, size_t ws_size,
                              hipStream_t stream) {
    const float* x      = (const float*)d_in[0];
    const float* conv_w = (const float*)d_in[1];
    const float* W1     = (const float*)d_in[2];
    const float* b1     = (const float*)d_in[3];
    const float* W2     = (const float*)d_in[4];
    const float* b2     = (const float*)d_in[5];
    const float* W3     = (const float*)d_in[6];
    const float* b3     = (const float*)d_in[7];
    float* out = (float*)d_out;

    char* ws = (char*)d_ws;
    bf16_t* W1f = (bf16_t*)(ws);
    bf16_t* W2f = (bf16_t*)(ws + (size_t)W1F_ELEMS * 2);
    bf16_t* W3f = (bf16_t*)(ws + (size_t)(W1F_ELEMS + W2F_ELEMS) * 2);
    if (ws_size < (size_t)(W1F_ELEMS + W2F_ELEMS + W3F_ELEMS) * 2) return;

    int prep_total = 800 * 320 + 320 * 320 + 320 * 16;  // 363520
    prep_weights<<<(prep_total + 255) / 256, 256, 0, stream>>>(
        conv_w, W1, W2, W3, W1f, W2f, W3f);

    fused_mlp<<<32768 / 64, 512, 0, stream>>>(
        x, b1, b2, b3, (const bf16x8*)W1f, (const bf16x8*)W2f,
        (const bf16x8*)W3f, out);
}